// Round 1
// baseline (240.457 us; speedup 1.0000x reference)
//
#include <hip/hip_runtime.h>
#include <stdint.h>

// MFMA fragment types per cdna_hip_programming.md §3 (compile-verified on gfx950)
typedef __attribute__((ext_vector_type(8))) short short8;  // 8 bf16 = 4 VGPRs
typedef __attribute__((ext_vector_type(4))) float f32x4;   // 4 fp32 acc

static_assert(sizeof(short8) == 16, "frag size");

__device__ __forceinline__ uint16_t f2bf(float f) {
  // round-to-nearest-even fp32 -> bf16 (inputs are finite)
  uint32_t u = __builtin_bit_cast(uint32_t, f);
  u += 0x7fffu + ((u >> 16) & 1u);
  return (uint16_t)(u >> 16);
}

__device__ __forceinline__ void gload_lds16(const void* g, void* lds_wave_base) {
  // async global->LDS, 16B/lane; LDS dst = wave-uniform base + lane*16
  __builtin_amdgcn_global_load_lds(
      (__attribute__((address_space(1))) void*)(void*)(g),
      (__attribute__((address_space(3))) void*)(lds_wave_base),
      16, 0, 0);
}

// ---------------------------------------------------------------------------
// Kernel A: dwT[o][i] = ternary(weight[i][o]) in {-1,0,+1} bf16,
// stored XOR-swizzled: element (o,i) at column i ^ ((o&7)<<3)  (flips 16B-chunk
// index within each 64-elem group -> conflict-free ds_read_b128 downstream).
// ---------------------------------------------------------------------------
__global__ __launch_bounds__(256) void quant_kernel(const float* __restrict__ w,
                                                    uint16_t* __restrict__ dwT) {
  const int o = blockIdx.x;   // 0..255 (out dim)
  const int i = threadIdx.x;  // 0..255 (in dim)
  const float v = w[i * 256 + o];
  const float t = (v > 0.01f) ? 1.0f : ((v < -0.01f) ? -1.0f : 0.0f);
  dwT[o * 256 + (i ^ ((o & 7) << 3))] = f2bf(t);
}

// ---------------------------------------------------------------------------
// Kernel 1: supportT[o][g] = 0.01 * sum_i x[g][i] * ternary[i][o]   (bf16 out)
//   g = b*2048 + m, flat over 16384 rows of x. Output XOR-swizzled like dwT.
// GEMM: M=256 (o, full, waves split it 64 each), N=64 (n-tile), K=256 (BK=64).
// A = dwT (bf16, staged via global_load_lds), B^T = x (fp32 -> bf16 in regs).
// ---------------------------------------------------------------------------
#define K1_A 0       // [256][64] bf16, row stride 128 B, 32768 B
#define K1_B 32768   // [64][64]  bf16, row stride 128 B,  8192 B

__global__ __launch_bounds__(256) void support_kernel(const float* __restrict__ x,
                                                      const uint16_t* __restrict__ dwT,
                                                      uint16_t* __restrict__ spt) {
  __shared__ __align__(16) unsigned char smem[32768 + 8192];
  const int t = threadIdx.x;
  const int lane = t & 63;
  const int w = t >> 6;          // wave id 0..3 -> o-slice [64w, 64w+64)
  const int wbase = w * 64;
  const int n0 = blockIdx.x * 64;
  const int r = lane & 15, q = lane >> 4, e = lane & 7;

  f32x4 acc[4][4] = {};          // acc[mi(o)][ni(n)]

  for (int k0 = 0; k0 < 256; k0 += 64) {
    // ---- stage A: dwT rows 0..255, cols [k0,k0+64) -- already bf16+swizzled
#pragma unroll
    for (int j = 0; j < 8; ++j) {
      const int idx = j * 256 + t;            // chunk id 0..2047
      const int row = idx >> 3, c = idx & 7;
      gload_lds16(dwT + (size_t)row * 256 + k0 + c * 8,
                  smem + K1_A + (size_t)(j * 256 + wbase) * 16);
    }
    // ---- stage B: x tile [64 n][64 i] fp32 -> bf16, swizzled chunks
#pragma unroll
    for (int it = 0; it < 4; ++it) {
      const int row = (t >> 4) + it * 16;     // 0..63
      const int c4 = t & 15;                  // float4 index
      const float4 v = *(const float4*)(x + (size_t)(n0 + row) * 256 + k0 + c4 * 4);
      const uint32_t lo = (uint32_t)f2bf(v.x) | ((uint32_t)f2bf(v.y) << 16);
      const uint32_t hi = (uint32_t)f2bf(v.z) | ((uint32_t)f2bf(v.w) << 16);
      const int chunk = c4 >> 1, half = c4 & 1;
      *(uint2*)(smem + K1_B + row * 128 + ((chunk ^ (row & 7)) << 4) + half * 8) =
          make_uint2(lo, hi);
    }
    __syncthreads();
    // ---- compute: 2 k-halves x 16 MFMA
#pragma unroll
    for (int h = 0; h < 2; ++h) {
      short8 av[4], bv[4];
      const int pc = ((h * 4 + q) ^ e) << 4;  // physical chunk byte offset
#pragma unroll
      for (int mi = 0; mi < 4; ++mi)
        av[mi] = *(const short8*)(smem + K1_A + (wbase + 16 * mi + r) * 128 + pc);
#pragma unroll
      for (int ni = 0; ni < 4; ++ni)
        bv[ni] = *(const short8*)(smem + K1_B + (16 * ni + r) * 128 + pc);
#pragma unroll
      for (int mi = 0; mi < 4; ++mi)
#pragma unroll
        for (int ni = 0; ni < 4; ++ni)
          acc[mi][ni] = __builtin_amdgcn_mfma_f32_16x16x32_bf16(av[mi], bv[ni],
                                                                acc[mi][ni], 0, 0, 0);
    }
    __syncthreads();
  }
  // ---- epilogue: scale by s=0.01 (exact fp32 mul), write bf16 swizzled
#pragma unroll
  for (int mi = 0; mi < 4; ++mi)
#pragma unroll
    for (int reg = 0; reg < 4; ++reg) {
      const int o = wbase + 16 * mi + q * 4 + reg;  // C row = M = o
      const int sw = (o & 7) << 3;
#pragma unroll
      for (int ni = 0; ni < 4; ++ni) {
        const int n = n0 + 16 * ni + r;             // C col = N = n
        spt[(size_t)o * 16384 + (n ^ sw)] = f2bf(acc[mi][ni][reg] * 0.01f);
      }
    }
}

// ---------------------------------------------------------------------------
// Kernel B: out[b][n][o] = relu( sum_m adj[b][n][m] * supportT[o][b*2048+m] + bias[o] )
// Block tile: M=64 (n) x N=256 (o, waves split 64 each), K=2048 in BK=64 steps.
// A = adj fp32 -> bf16, LDS pad to 72 elems/row (conflict-free frag reads).
// B = supportT bf16 via global_load_lds dwordx4 (verbatim copy of swizzled rows).
// Grid: 256 blocks = 8 batches x 32 n-tiles; bb = blockIdx%8 -> one batch/XCD.
// ---------------------------------------------------------------------------
#define KB_A 0       // [64][72] bf16, row stride 144 B, 9216 B
#define KB_B 9216    // [256][64] bf16, row stride 128 B, 32768 B

__global__ __launch_bounds__(256) void gcn_main_kernel(const float* __restrict__ adj,
                                                       const uint16_t* __restrict__ spt,
                                                       const float* __restrict__ bias,
                                                       float* __restrict__ out) {
  __shared__ __align__(16) unsigned char smem[9216 + 32768];
  const int t = threadIdx.x;
  const int lane = t & 63;
  const int w = t >> 6;
  const int wbase = w * 64;                 // wave's o-slice base
  const int bb = blockIdx.x & 7;            // batch
  const int n0 = (blockIdx.x >> 3) * 64;    // n-tile
  const float* adjb = adj + (size_t)bb * 2048 * 2048;
  const int r = lane & 15, q = lane >> 4, e = lane & 7;

  f32x4 acc[4][4] = {};                     // acc[mi(n)][ni(o)]

  for (int k0 = 0; k0 < 2048; k0 += 64) {
    // ---- stage A: adj tile [64 n][64 m] fp32 -> bf16, padded stride 72
#pragma unroll
    for (int it = 0; it < 4; ++it) {
      const int row = (t >> 4) + it * 16;
      const int c4 = t & 15;
      const float4 v = *(const float4*)(adjb + (size_t)(n0 + row) * 2048 + k0 + c4 * 4);
      const uint32_t lo = (uint32_t)f2bf(v.x) | ((uint32_t)f2bf(v.y) << 16);
      const uint32_t hi = (uint32_t)f2bf(v.z) | ((uint32_t)f2bf(v.w) << 16);
      *(uint2*)(smem + KB_A + row * 144 + c4 * 8) = make_uint2(lo, hi);
    }
    // ---- stage B: supportT tile [256 o][64 m] bf16, async direct-to-LDS
#pragma unroll
    for (int j = 0; j < 8; ++j) {
      const int idx = j * 256 + t;
      const int row = idx >> 3, c = idx & 7;
      gload_lds16(spt + (size_t)row * 16384 + bb * 2048 + k0 + c * 8,
                  smem + KB_B + (size_t)(j * 256 + wbase) * 16);
    }
    __syncthreads();
    // ---- compute
#pragma unroll
    for (int h = 0; h < 2; ++h) {
      short8 av[4], bv[4];
      const int pc = ((h * 4 + q) ^ e) << 4;
#pragma unroll
      for (int mi = 0; mi < 4; ++mi)
        av[mi] = *(const short8*)(smem + KB_A + (16 * mi + r) * 144 + h * 64 + q * 16);
#pragma unroll
      for (int ni = 0; ni < 4; ++ni)
        bv[ni] = *(const short8*)(smem + KB_B + (wbase + 16 * ni + r) * 128 + pc);
#pragma unroll
      for (int mi = 0; mi < 4; ++mi)
#pragma unroll
        for (int ni = 0; ni < 4; ++ni)
          acc[mi][ni] = __builtin_amdgcn_mfma_f32_16x16x32_bf16(av[mi], bv[ni],
                                                                acc[mi][ni], 0, 0, 0);
    }
    __syncthreads();
  }
  // ---- epilogue: + bias, relu, fp32 store
#pragma unroll
  for (int ni = 0; ni < 4; ++ni) {
    const int o = wbase + 16 * ni + r;      // C col = N = o
    const float bs = bias[o];
#pragma unroll
    for (int mi = 0; mi < 4; ++mi)
#pragma unroll
      for (int reg = 0; reg < 4; ++reg) {
        const int n = n0 + 16 * mi + q * 4 + reg;  // C row = M = n
        const float val = acc[mi][ni][reg] + bs;
        out[((size_t)bb * 2048 + n) * 256 + o] = fmaxf(val, 0.0f);
      }
  }
}

// ---------------------------------------------------------------------------
extern "C" void kernel_launch(void* const* d_in, const int* in_sizes, int n_in,
                              void* d_out, int out_size, void* d_ws, size_t ws_size,
                              hipStream_t stream) {
  const float* x      = (const float*)d_in[0];  // [8,2048,256]
  const float* adj    = (const float*)d_in[1];  // [8,2048,2048]
  const float* weight = (const float*)d_in[2];  // [256,256]
  const float* bias   = (const float*)d_in[3];  // [256]
  float* out = (float*)d_out;                   // [8,2048,256]

  uint16_t* dwT = (uint16_t*)d_ws;                          // 256*256 bf16 = 128 KB
  uint16_t* spt = (uint16_t*)((char*)d_ws + 131072);        // 256*16384 bf16 = 8 MB

  hipLaunchKernelGGL(quant_kernel,    dim3(256), dim3(256), 0, stream, weight, dwT);
  hipLaunchKernelGGL(support_kernel,  dim3(256), dim3(256), 0, stream, x, dwT, spt);
  hipLaunchKernelGGL(gcn_main_kernel, dim3(256), dim3(256), 0, stream, adj, spt, bias, out);
}